// Round 7
// baseline (110.804 us; speedup 1.0000x reference)
//
#include <hip/hip_runtime.h>

#define CIN   256
#define COUT  256
#define HH    64
#define WW    64
#define KD    2304         // CIN * 9
#define NPIX  16384        // B * HO * WO
#define SPLIT 16
#define CPS   (CIN / SPLIT)

typedef __attribute__((ext_vector_type(8))) short  short8v;
typedef __attribute__((ext_vector_type(4))) float  float4v;
typedef __attribute__((ext_vector_type(2))) unsigned int uint2v;
typedef _Float16 h2 __attribute__((ext_vector_type(2)));
typedef _Float16 h8 __attribute__((ext_vector_type(8)));
typedef unsigned int u32;
typedef unsigned short u16;

__device__ __forceinline__ h2 as_h2(u32 v) { union { u32 u; h2 h; } x; x.u = v; return x.h; }
__device__ __forceinline__ u32 as_u32(h2 h) { union { u32 u; h2 h; } x; x.h = h; return x.u; }
__device__ __forceinline__ u16 f2h_bits(float f) { _Float16 h = (_Float16)f; return *(u16*)&h; }

__device__ __forceinline__ void gload_lds16(const void* g, void* l) {
  __builtin_amdgcn_global_load_lds((const __attribute__((address_space(1))) u32*)g,
                                   (__attribute__((address_space(3))) u32*)l, 16, 0, 0);
}

// ---------------- Kernel 1a: offset/mask partials, channel-split ----------------
__global__ __launch_bounds__(256) void offmask_part_kernel(
    const float* __restrict__ x,
    const float* __restrict__ off_dw, const float* __restrict__ off_pw,
    const float* __restrict__ mask_dw, const float* __restrict__ mask_pw,
    float* __restrict__ part)
{
  int m = blockIdx.x * 256 + threadIdx.x;   // pixel id: b*4096 + ho*64 + wo
  int s = blockIdx.y;                        // channel split 0..SPLIT-1
  int b = m >> 12, pix = m & 4095;
  int ho = pix >> 6, wo = pix & 63;
  const float* xb = x + (size_t)b * CIN * 4096;

  float acc[27];
#pragma unroll
  for (int j = 0; j < 27; ++j) acc[j] = 0.f;

  int c0 = s * CPS;
  for (int ci = 0; ci < CPS; ++ci) {
    int c = c0 + ci;
    const float* xc = xb + (size_t)c * 4096;
    float d_off = 0.f, d_msk = 0.f;
#pragma unroll
    for (int t = 0; t < 9; ++t) {
      int gy = ho + t / 3 - 1, gx = wo + t % 3 - 1;
      bool ok = (gy >= 0) & (gy < HH) & (gx >= 0) & (gx < WW);
      float v = ok ? xc[gy * 64 + gx] : 0.f;
      d_off += v * off_dw[c * 9 + t];
      d_msk += v * mask_dw[c * 9 + t];
    }
#pragma unroll
    for (int j = 0; j < 18; ++j) acc[j] += d_off * off_pw[j * 256 + c];
#pragma unroll
    for (int j = 0; j < 9; ++j) acc[18 + j] += d_msk * mask_pw[j * 256 + c];
  }
  float* pp = part + ((size_t)s * NPIX + m) * 32;
#pragma unroll
  for (int j = 0; j < 27; ++j) pp[j] = acc[j];
}

// ---------------- Kernel 1b: reduce partials -> rec (sigmoid on mask) ----------------
__global__ __launch_bounds__(256) void offmask_reduce_kernel(
    const float* __restrict__ part, float* __restrict__ rec)
{
  int i = blockIdx.x * 256 + threadIdx.x;   // over NPIX*32
  int m = i >> 5, j = i & 31;
  if (j >= 27) { rec[i] = 0.f; return; }
  float sum = 0.f;
#pragma unroll
  for (int s = 0; s < SPLIT; ++s) sum += part[((size_t)s * NPIX + m) * 32 + j];
  rec[i] = (j < 18) ? sum : 2.f / (1.f + __expf(-sum));
}

// ---------------- Kernel 2: weight f32 (co,c,ki,kj) -> f16 [co][kk*256 + c] ----------------
__global__ __launch_bounds__(256) void wconv_kernel(const float* __restrict__ w,
                                                    u16* __restrict__ wb)
{
  int i = blockIdx.x * 256 + threadIdx.x;     // over COUT*KD
  int co = i / KD, rem = i - co * KD;
  int c = rem / 9, kk = rem - c * 9;
  wb[co * KD + kk * 256 + c] = f2h_bits(w[i]);
}

// ---------------- Kernel 2b: x NCHW f32 -> xt NHWC f16 ----------------
__global__ __launch_bounds__(256) void xpose_kernel(const float* __restrict__ x,
                                                    u16* __restrict__ xt)
{
  __shared__ float t[64][65];
  int ptile = blockIdx.x;   // 64-pixel tile within image (0..63)
  int ctile = blockIdx.y;   // 64-channel tile (0..3)
  int b     = blockIdx.z;
  int tid = threadIdx.x;
  const float* xb = x + (size_t)b * CIN * 4096 + (size_t)ctile * 64 * 4096 + ptile * 64;
#pragma unroll
  for (int i = 0; i < 16; ++i) {
    int c = i * 4 + (tid >> 6), p = tid & 63;
    t[c][p] = xb[(size_t)c * 4096 + p];
  }
  __syncthreads();
  u16* xo = xt + ((size_t)b * 4096 + ptile * 64) * 256 + ctile * 64;
#pragma unroll
  for (int i = 0; i < 16; ++i) {
    int p = i * 4 + (tid >> 6), c = tid & 63;
    xo[(size_t)p * 256 + c] = f2h_bits(t[c][p]);
  }
}

// ---------------- Kernel 4: FUSED deformable-im2col + GEMM, K-split x4, f16 ----------------
// Grid 1024: bid = (ptile<<2)|h. Half h covers channels h*64..h*64+63 for all
// 9 taps: K=576, 18 steps of 32. 4 blocks/CU (LDS 40KB x4 = 160KB exactly),
// 8 waves/SIMD -> 4 independent barrier-groups overlap VALU/LDS/MFMA pipes.
// Blend in packed f16 (v_pk_fma_f16): 8 pk-fma/thread/step, no conversions.
// Swizzle (rule #21): slot' = slot ^ (r&3) ^ ((r>>2)&3) on A gload SOURCE
// (linear dest), B ds_write slot, and frag ds_reads (proven R5/R6).
__global__ __launch_bounds__(512) void gemm_fused_kernel(
    const u16* __restrict__ A,     // wb f16 [COUT][KD]
    const u16* __restrict__ xt,    // NHWC f16 [B*4096][256]
    const float* __restrict__ rec, // [NPIX][32]
    const float* __restrict__ bias,
    float* __restrict__ out,       // h==0 dest (+bias)
    float* __restrict__ tmp)       // h>=1 dest: tmp + (h-1)*COUT*NPIX
{
  __shared__ __align__(16) u16 lA[2][256 * 32];   // 2 x 16 KB
  __shared__ __align__(16) u16 lB[2][64 * 32];    // 2 x 4 KB
  const int tid = threadIdx.x;
  const int bid = blockIdx.x;            // 0..1023
  const int h   = bid & 3;               // K quarter
  const int ptile = bid >> 2;            // 0..255
  const int m0  = ptile * 64;            // pixel tile base
  const int b_img = ptile >> 6;
  const int cbase = h * 64;              // channel base of this quarter
  const int wave = tid >> 6, lane = tid & 63;
  const int wm = wave >> 1, wn = wave & 1;
  const int rl = lane & 15, kq = lane >> 4;
  const int sA = (kq ^ (rl & 3) ^ ((rl >> 2) & 3)) * 8;   // frag read slot (u16)

  // A staging: thread covers rows (tid>>2) and (tid>>2)+128, 16B each
  const int rA  = tid >> 2;
  const int koA = ((tid & 3) ^ (rA & 3) ^ ((rA >> 2) & 3)) * 8;
  const u16* aRow0 = A + (size_t)rA * KD + koA;
  const u16* aRow1 = A + (size_t)(rA + 128) * KD + koA;

  // B sampling: thread -> (pixel spx, 4 channels sc4 within current 32-chunk)
  const int spx = tid >> 3;              // 0..63
  const int sc4 = (tid & 7) * 4;         // 0,4,..,28
  const int m_px = m0 + spx;
  const int ho = (m_px & 4095) >> 6, wo = m_px & 63;
  const float* rp = rec + (size_t)m_px * 32;
  const u16* xb = xt + (size_t)b_img * 4096 * 256;
  const int wAddr = spx * 32 +
                    ((((tid >> 1) & 3) ^ ((spx & 3) ^ ((spx >> 2) & 3))) * 8) +
                    (tid & 1) * 4;

  u32 cOff[4];   // corner row element-offsets into xb
  h2  wh[4];     // corner weights broadcast as half2 (incl. mask)

  // step t (0..17): kk = t>>1, chunk col = kk*256 + cbase + (t&1)*32
#define KCOL(t_) (((t_) >> 1) * 256 + cbase + ((t_) & 1) * 32)

#define CALC_CORNERS(kk_) do {                                             \
    float dy = rp[(kk_) * 2], dx = rp[(kk_) * 2 + 1], msk = rp[18 + (kk_)];\
    float py  = (float)(ho - 1 + ((kk_) / 3)) + dy;                        \
    float pxf = (float)(wo - 1 + ((kk_) % 3)) + dx;                        \
    float fy = floorf(py), fx = floorf(pxf);                               \
    int y0 = (int)fy, x0 = (int)fx;                                        \
    float wy1 = py - fy, wy0 = 1.f - wy1;                                  \
    float wx1 = pxf - fx, wx0 = 1.f - wx1;                                 \
    _Pragma("unroll")                                                      \
    for (int cr = 0; cr < 4; ++cr) {                                       \
      int iy = y0 + (cr >> 1), ix = x0 + (cr & 1);                         \
      bool valid = (iy >= 0) & (iy < HH) & (ix >= 0) & (ix < WW);          \
      int iyc = min(max(iy, 0), HH - 1), ixc = min(max(ix, 0), WW - 1);    \
      cOff[cr] = (u32)(iyc * 64 + ixc) * 256;                              \
      float wy = (cr >> 1) ? wy1 : wy0;                                    \
      float wx = (cr & 1) ? wx1 : wx0;                                     \
      float wf = valid ? (wy * wx * msk) : 0.f;                            \
      _Float16 hw = (_Float16)wf;                                          \
      wh[cr] = (h2){hw, hw};                                               \
    }                                                                      \
  } while (0)

#define STAGE_A(t, bufi) do {                                              \
    int k0_ = KCOL(t);                                                     \
    gload_lds16(aRow0 + k0_, lA[bufi] + tid * 8);                          \
    gload_lds16(aRow1 + k0_, lA[bufi] + (tid + 512) * 8);                  \
  } while (0)

#define BLEND_WRITE(bufi, v0_, v1_, v2_, v3_) do {                         \
    h2 a01 = wh[0] * as_h2((v0_)[0]) + wh[1] * as_h2((v1_)[0]);            \
    a01   += wh[2] * as_h2((v2_)[0]) + wh[3] * as_h2((v3_)[0]);            \
    h2 a23 = wh[0] * as_h2((v0_)[1]) + wh[1] * as_h2((v1_)[1]);            \
    a23   += wh[2] * as_h2((v2_)[1]) + wh[3] * as_h2((v3_)[1]);            \
    uint2v wv; wv[0] = as_u32(a01); wv[1] = as_u32(a23);                   \
    *(uint2v*)&lB[bufi][wAddr] = wv;                                       \
  } while (0)

  float4v acc[4][2];
#pragma unroll
  for (int m = 0; m < 4; ++m)
#pragma unroll
    for (int n = 0; n < 2; ++n) acc[m][n] = float4v{0.f, 0.f, 0.f, 0.f};

  // ---- prologue: sample K-step 0 into lB[0], stage A(0) ----
  {
    CALC_CORNERS(0);
    int c0n = cbase + sc4;
    uint2v v0 = *(const uint2v*)(xb + cOff[0] + c0n);
    uint2v v1 = *(const uint2v*)(xb + cOff[1] + c0n);
    uint2v v2 = *(const uint2v*)(xb + cOff[2] + c0n);
    uint2v v3 = *(const uint2v*)(xb + cOff[3] + c0n);
    BLEND_WRITE(0, v0, v1, v2, v3);
    STAGE_A(0, 0);
  }
  __syncthreads();

#pragma unroll 2
  for (int ks = 0; ks < 18; ++ks) {
    const int cur = ks & 1;
    uint2v v0, v1, v2, v3;
    const bool have = (ks < 17);
    if (have) {
      STAGE_A(ks + 1, cur ^ 1);
      int ksn = ks + 1;
      if ((ksn & 1) == 0) CALC_CORNERS(ksn >> 1);
      int c0n = cbase + (ksn & 1) * 32 + sc4;
      v0 = *(const uint2v*)(xb + cOff[0] + c0n);
      v1 = *(const uint2v*)(xb + cOff[1] + c0n);
      v2 = *(const uint2v*)(xb + cOff[2] + c0n);
      v3 = *(const uint2v*)(xb + cOff[3] + c0n);
    }
    h8 af[4], bf[2];
#pragma unroll
    for (int m = 0; m < 4; ++m)
      af[m] = *(const h8*)&lA[cur][(wm * 64 + m * 16 + rl) * 32 + sA];
#pragma unroll
    for (int n = 0; n < 2; ++n)
      bf[n] = *(const h8*)&lB[cur][(wn * 32 + n * 16 + rl) * 32 + sA];
#pragma unroll
    for (int m = 0; m < 4; ++m)
#pragma unroll
      for (int n = 0; n < 2; ++n)
        acc[m][n] = __builtin_amdgcn_mfma_f32_16x16x32_f16(af[m], bf[n], acc[m][n], 0, 0, 0);
    if (have) BLEND_WRITE(cur ^ 1, v0, v1, v2, v3);
    __syncthreads();
  }
#undef STAGE_A
#undef CALC_CORNERS
#undef BLEND_WRITE
#undef KCOL

  const int p_base = (m0 & 4095) + wn * 32;
  float* db = (h ? (tmp + (size_t)(h - 1) * COUT * NPIX) : out) +
              (size_t)b_img * COUT * 4096;
#pragma unroll
  for (int m = 0; m < 4; ++m) {
#pragma unroll
    for (int j = 0; j < 4; ++j) {
      int co = wm * 64 + m * 16 + kq * 4 + j;
      float bv = h ? 0.f : bias[co];
#pragma unroll
      for (int n = 0; n < 2; ++n) {
        int pp = p_base + n * 16 + rl;
        db[(size_t)co * 4096 + pp] = acc[m][n][j] + bv;
      }
    }
  }
}

// ---------------- Kernel 5: out += tmp0 + tmp1 + tmp2 ----------------
__global__ __launch_bounds__(256) void add_kernel(float* __restrict__ out,
                                                  const float* __restrict__ tmp)
{
  size_t i = ((size_t)blockIdx.x * 256 + threadIdx.x) * 4;
  float4v a  = *(const float4v*)(out + i);
  float4v b0 = *(const float4v*)(tmp + i);
  float4v b1 = *(const float4v*)(tmp + (size_t)COUT * NPIX + i);
  float4v b2 = *(const float4v*)(tmp + (size_t)2 * COUT * NPIX + i);
  a += b0 + b1 + b2;
  *(float4v*)(out + i) = a;
}

extern "C" void kernel_launch(void* const* d_in, const int* in_sizes, int n_in,
                              void* d_out, int out_size, void* d_ws, size_t ws_size,
                              hipStream_t stream) {
  const float* x       = (const float*)d_in[0];
  const float* weight  = (const float*)d_in[1];
  const float* bias    = (const float*)d_in[2];
  const float* off_dw  = (const float*)d_in[3];
  const float* off_pw  = (const float*)d_in[4];
  const float* mask_dw = (const float*)d_in[5];
  const float* mask_pw = (const float*)d_in[6];

  // ws layout: rec 2MB @0 | wb 1.18MB @2,097,152 | xt 8.39MB @3,276,800 |
  //            tmp 3x16.78MB @11,665,408 (part 33.5MB aliases tmp; consumed
  //            by reduce before gemm writes tmp)  => total 61,997,056 B
  if (ws_size < 61997056ull) return;
  float* rec  = (float*)d_ws;
  u16*   wb   = (u16*)((char*)d_ws + 2097152);
  u16*   xt   = (u16*)((char*)d_ws + 3276800);
  float* part = (float*)((char*)d_ws + 11665408);
  float* tmp  = part;                       // alias: part consumed before gemm
  float* out  = (float*)d_out;

  wconv_kernel<<<dim3(2304), dim3(256), 0, stream>>>(weight, wb);
  offmask_part_kernel<<<dim3(NPIX / 256, SPLIT), dim3(256), 0, stream>>>(
      x, off_dw, off_pw, mask_dw, mask_pw, part);
  offmask_reduce_kernel<<<dim3(NPIX * 32 / 256), dim3(256), 0, stream>>>(part, rec);
  xpose_kernel<<<dim3(64, 4, 4), dim3(256), 0, stream>>>(x, xt);
  gemm_fused_kernel<<<dim3(1024), dim3(512), 0, stream>>>(wb, xt, rec, bias, out, tmp);
  add_kernel<<<dim3(COUT * NPIX / 4 / 256), dim3(256), 0, stream>>>(out, tmp);
}

// Round 8
// 107.055 us; speedup vs baseline: 1.0350x; 1.0350x over previous
//
#include <hip/hip_runtime.h>

#define CIN   256
#define COUT  256
#define HH    64
#define WW    64
#define KD    2304         // CIN * 9
#define NPIX  16384        // B * HO * WO
#define SPLIT 16
#define CPS   (CIN / SPLIT)
#define NSTEP 36           // K per half = 1152 = 36 x 32

typedef __attribute__((ext_vector_type(4))) float  float4v;
typedef __attribute__((ext_vector_type(2))) unsigned int uint2v;
typedef _Float16 h2 __attribute__((ext_vector_type(2)));
typedef _Float16 h8 __attribute__((ext_vector_type(8)));
typedef unsigned int u32;
typedef unsigned short u16;

__device__ __forceinline__ h2 as_h2(u32 v) { union { u32 u; h2 h; } x; x.u = v; return x.h; }
__device__ __forceinline__ u32 as_u32(h2 h) { union { u32 u; h2 h; } x; x.h = h; return x.u; }
__device__ __forceinline__ u16 f2h_bits(float f) { _Float16 h = (_Float16)f; return *(u16*)&h; }

__device__ __forceinline__ void gload_lds16(const void* g, void* l) {
  __builtin_amdgcn_global_load_lds((const __attribute__((address_space(1))) u32*)g,
                                   (__attribute__((address_space(3))) u32*)l, 16, 0, 0);
}

// ---------------- Kernel 1a: offset/mask partials, channel-split ----------------
__global__ __launch_bounds__(256) void offmask_part_kernel(
    const float* __restrict__ x,
    const float* __restrict__ off_dw, const float* __restrict__ off_pw,
    const float* __restrict__ mask_dw, const float* __restrict__ mask_pw,
    float* __restrict__ part)
{
  int m = blockIdx.x * 256 + threadIdx.x;   // pixel id: b*4096 + ho*64 + wo
  int s = blockIdx.y;                        // channel split 0..SPLIT-1
  int b = m >> 12, pix = m & 4095;
  int ho = pix >> 6, wo = pix & 63;
  const float* xb = x + (size_t)b * CIN * 4096;

  float acc[27];
#pragma unroll
  for (int j = 0; j < 27; ++j) acc[j] = 0.f;

  int c0 = s * CPS;
  for (int ci = 0; ci < CPS; ++ci) {
    int c = c0 + ci;
    const float* xc = xb + (size_t)c * 4096;
    float d_off = 0.f, d_msk = 0.f;
#pragma unroll
    for (int t = 0; t < 9; ++t) {
      int gy = ho + t / 3 - 1, gx = wo + t % 3 - 1;
      bool ok = (gy >= 0) & (gy < HH) & (gx >= 0) & (gx < WW);
      float v = ok ? xc[gy * 64 + gx] : 0.f;
      d_off += v * off_dw[c * 9 + t];
      d_msk += v * mask_dw[c * 9 + t];
    }
#pragma unroll
    for (int j = 0; j < 18; ++j) acc[j] += d_off * off_pw[j * 256 + c];
#pragma unroll
    for (int j = 0; j < 9; ++j) acc[18 + j] += d_msk * mask_pw[j * 256 + c];
  }
  float* pp = part + ((size_t)s * NPIX + m) * 32;
#pragma unroll
  for (int j = 0; j < 27; ++j) pp[j] = acc[j];
}

// ---------------- Kernel 1b: reduce partials -> rec (sigmoid on mask) ----------------
__global__ __launch_bounds__(256) void offmask_reduce_kernel(
    const float* __restrict__ part, float* __restrict__ rec)
{
  int i = blockIdx.x * 256 + threadIdx.x;   // over NPIX*32
  int m = i >> 5, j = i & 31;
  if (j >= 27) { rec[i] = 0.f; return; }
  float sum = 0.f;
#pragma unroll
  for (int s = 0; s < SPLIT; ++s) sum += part[((size_t)s * NPIX + m) * 32 + j];
  rec[i] = (j < 18) ? sum : 2.f / (1.f + __expf(-sum));
}

// ---------------- Kernel 2: weight f32 (co,c,ki,kj) -> f16 [co][kk*256 + c] ----------------
__global__ __launch_bounds__(256) void wconv_kernel(const float* __restrict__ w,
                                                    u16* __restrict__ wb)
{
  int i = blockIdx.x * 256 + threadIdx.x;     // over COUT*KD
  int co = i / KD, rem = i - co * KD;
  int c = rem / 9, kk = rem - c * 9;
  wb[co * KD + kk * 256 + c] = f2h_bits(w[i]);
}

// ---------------- Kernel 2b: x NCHW f32 -> xt NHWC f16 ----------------
__global__ __launch_bounds__(256) void xpose_kernel(const float* __restrict__ x,
                                                    u16* __restrict__ xt)
{
  __shared__ float t[64][65];
  int ptile = blockIdx.x;   // 64-pixel tile within image (0..63)
  int ctile = blockIdx.y;   // 64-channel tile (0..3)
  int b     = blockIdx.z;
  int tid = threadIdx.x;
  const float* xb = x + (size_t)b * CIN * 4096 + (size_t)ctile * 64 * 4096 + ptile * 64;
#pragma unroll
  for (int i = 0; i < 16; ++i) {
    int c = i * 4 + (tid >> 6), p = tid & 63;
    t[c][p] = xb[(size_t)c * 4096 + p];
  }
  __syncthreads();
  u16* xo = xt + ((size_t)b * 4096 + ptile * 64) * 256 + ctile * 64;
#pragma unroll
  for (int i = 0; i < 16; ++i) {
    int p = i * 4 + (tid >> 6), c = tid & 63;
    xo[(size_t)p * 256 + c] = f2h_bits(t[c][p]);
  }
}

// ---------------- Kernel 4: FUSED im2col+GEMM, K-split x2, counted vmcnt ----------------
// Grid 512: bid=(ptile<<1)|h; half h = channels h*128..h*128+127, all 9 taps:
// K=1152, 36 steps of 32. Triple-buffered A DMA (2-deep prefetch) + B dbuf.
// Per step: samp(t+1) -> DMA A(t+2) -> frag+MFMA(t) -> vmcnt(2) [A(t+2) stays
// in flight ACROSS the barrier - T4] -> blend/ds_write B(t+1) -> lgkmcnt(0) ->
// raw s_barrier. One barrier/step; vmcnt never 0 in steady state.
// Race audit: DMA(t+2) targets lA[(t-1)%3], readers done before the barrier it
// follows; B write targets lB[(t+1)&1]=lB[(t-1)&1], same argument.
__global__ __launch_bounds__(512, 4) void gemm_fused_kernel(
    const u16* __restrict__ A,     // wb f16 [COUT][KD]
    const u16* __restrict__ xt,    // NHWC f16 [B*4096][256]
    const float* __restrict__ rec, // [NPIX][32]
    const float* __restrict__ bias,
    float* __restrict__ out,       // h==0 dest (+bias)
    float* __restrict__ tmp)       // h==1 dest (raw)
{
  __shared__ __align__(16) u16 lA[3][256 * 32];   // 3 x 16 KB
  __shared__ __align__(16) u16 lB[2][64 * 32];    // 2 x 4 KB
  const int tid = threadIdx.x;
  const int bid = blockIdx.x;            // 0..511
  const int h   = bid & 1;
  const int ptile = bid >> 1;            // 0..255
  const int m0  = ptile * 64;
  const int b_img = ptile >> 6;
  const int cbase = h * 128;
  const int wave = tid >> 6, lane = tid & 63;
  const int wm = wave >> 1, wn = wave & 1;
  const int rl = lane & 15, kq = lane >> 4;
  const int sA = (kq ^ (rl & 3) ^ ((rl >> 2) & 3)) * 8;   // frag read slot (u16)

  // A staging: thread covers rows (tid>>2) and (tid>>2)+128, 16B each
  const int rA  = tid >> 2;
  const int koA = ((tid & 3) ^ (rA & 3) ^ ((rA >> 2) & 3)) * 8;
  const u16* aRow0 = A + (size_t)rA * KD + koA;
  const u16* aRow1 = A + (size_t)(rA + 128) * KD + koA;

  // B sampling: thread -> (pixel spx, 4 channels sc4 within current 32-chunk)
  const int spx = tid >> 3;              // 0..63
  const int sc4 = (tid & 7) * 4;         // 0,4,..,28
  const int m_px = m0 + spx;
  const int ho = (m_px & 4095) >> 6, wo = m_px & 63;
  const float* rp = rec + (size_t)m_px * 32;
  const u16* xb = xt + (size_t)b_img * 4096 * 256;
  const int wAddr = spx * 32 +
                    ((((tid >> 1) & 3) ^ ((spx & 3) ^ ((spx >> 2) & 3))) * 8) +
                    (tid & 1) * 4;

  u32 cOff[4];   // corner row element-offsets into xb
  h2  wh[4];     // corner weights broadcast as half2 (incl. mask)

  // step t: kk = t>>2, chunk col = kk*256 + cbase + (t&3)*32
#define KCOL(t_) (((t_) >> 2) * 256 + cbase + ((t_) & 3) * 32)

#define CALC_CORNERS(kk_) do {                                             \
    float dy = rp[(kk_) * 2], dx = rp[(kk_) * 2 + 1], msk = rp[18 + (kk_)];\
    float py  = (float)(ho - 1 + ((kk_) / 3)) + dy;                        \
    float pxf = (float)(wo - 1 + ((kk_) % 3)) + dx;                        \
    float fy = floorf(py), fx = floorf(pxf);                               \
    int y0 = (int)fy, x0 = (int)fx;                                        \
    float wy1 = py - fy, wy0 = 1.f - wy1;                                  \
    float wx1 = pxf - fx, wx0 = 1.f - wx1;                                 \
    _Pragma("unroll")                                                      \
    for (int cr = 0; cr < 4; ++cr) {                                       \
      int iy = y0 + (cr >> 1), ix = x0 + (cr & 1);                         \
      bool valid = (iy >= 0) & (iy < HH) & (ix >= 0) & (ix < WW);          \
      int iyc = min(max(iy, 0), HH - 1), ixc = min(max(ix, 0), WW - 1);    \
      cOff[cr] = (u32)(iyc * 64 + ixc) * 256;                              \
      float wy = (cr >> 1) ? wy1 : wy0;                                    \
      float wx = (cr & 1) ? wx1 : wx0;                                     \
      float wf = valid ? (wy * wx * msk) : 0.f;                            \
      _Float16 hw = (_Float16)wf;                                          \
      wh[cr] = (h2){hw, hw};                                               \
    }                                                                      \
  } while (0)

#define STAGE_A(k_, slot_) do {                                            \
    int k0_ = KCOL(k_);                                                    \
    gload_lds16(aRow0 + k0_, lA[slot_] + tid * 8);                         \
    gload_lds16(aRow1 + k0_, lA[slot_] + (tid + 512) * 8);                 \
  } while (0)

#define BLEND_WRITE(bufi_, v0_, v1_, v2_, v3_) do {                        \
    h2 a01 = wh[0] * as_h2((v0_)[0]) + wh[1] * as_h2((v1_)[0]);            \
    a01   += wh[2] * as_h2((v2_)[0]) + wh[3] * as_h2((v3_)[0]);            \
    h2 a23 = wh[0] * as_h2((v0_)[1]) + wh[1] * as_h2((v1_)[1]);            \
    a23   += wh[2] * as_h2((v2_)[1]) + wh[3] * as_h2((v3_)[1]);            \
    uint2v wv; wv[0] = as_u32(a01); wv[1] = as_u32(a23);                   \
    *(uint2v*)&lB[bufi_][wAddr] = wv;                                      \
  } while (0)

  float4v acc[4][2];
#pragma unroll
  for (int m = 0; m < 4; ++m)
#pragma unroll
    for (int n = 0; n < 2; ++n) acc[m][n] = float4v{0.f, 0.f, 0.f, 0.f};

  // ---- prologue: samp(0) -> A(0) -> A(1); vmcnt(2) drains samp+A(0) ----
  {
    CALC_CORNERS(0);
    int c0n = cbase + sc4;
    uint2v v0 = *(const uint2v*)(xb + cOff[0] + c0n);
    uint2v v1 = *(const uint2v*)(xb + cOff[1] + c0n);
    uint2v v2 = *(const uint2v*)(xb + cOff[2] + c0n);
    uint2v v3 = *(const uint2v*)(xb + cOff[3] + c0n);
    STAGE_A(0, 0);
    STAGE_A(1, 1);
    asm volatile("s_waitcnt vmcnt(2)" ::: "memory");
    BLEND_WRITE(0, v0, v1, v2, v3);
    asm volatile("s_waitcnt lgkmcnt(0)" ::: "memory");
    __builtin_amdgcn_s_barrier();
  }

  for (int it = 0; it < 6; ++it) {
#pragma unroll
    for (int u = 0; u < 6; ++u) {
      const int t = it * 6 + u;
      const int tn  = (t + 1 == NSTEP) ? 0 : t + 1;              // samp idx
      const int tn2 = (t + 2 >= NSTEP) ? (t + 2 - NSTEP) : t + 2; // DMA idx
      // sample step t+1 (issued first: oldest after A(t+1))
      if ((tn & 3) == 0) CALC_CORNERS(tn >> 2);
      int c0n = cbase + (tn & 3) * 32 + sc4;
      uint2v v0 = *(const uint2v*)(xb + cOff[0] + c0n);
      uint2v v1 = *(const uint2v*)(xb + cOff[1] + c0n);
      uint2v v2 = *(const uint2v*)(xb + cOff[2] + c0n);
      uint2v v3 = *(const uint2v*)(xb + cOff[3] + c0n);
      // DMA step t+2 (newest; survives this step's vmcnt(2))
      STAGE_A(tn2, (u + 2) % 3);
      // frags + MFMA on step t
      h8 af[4], bf[2];
#pragma unroll
      for (int m = 0; m < 4; ++m)
        af[m] = *(const h8*)&lA[u % 3][(wm * 64 + m * 16 + rl) * 32 + sA];
#pragma unroll
      for (int n = 0; n < 2; ++n)
        bf[n] = *(const h8*)&lB[u & 1][(wn * 32 + n * 16 + rl) * 32 + sA];
#pragma unroll
      for (int m = 0; m < 4; ++m)
#pragma unroll
        for (int n = 0; n < 2; ++n)
          acc[m][n] = __builtin_amdgcn_mfma_f32_16x16x32_f16(af[m], bf[n], acc[m][n], 0, 0, 0);
      // A(t+1)+samples landed; A(t+2) stays in flight across the barrier
      asm volatile("s_waitcnt vmcnt(2)" ::: "memory");
      BLEND_WRITE((u + 1) & 1, v0, v1, v2, v3);
      asm volatile("s_waitcnt lgkmcnt(0)" ::: "memory");
      __builtin_amdgcn_s_barrier();
    }
  }
#undef STAGE_A
#undef CALC_CORNERS
#undef BLEND_WRITE
#undef KCOL

  const int p_base = (m0 & 4095) + wn * 32;
  float* db = (h ? tmp : out) + (size_t)b_img * COUT * 4096;
#pragma unroll
  for (int m = 0; m < 4; ++m) {
#pragma unroll
    for (int j = 0; j < 4; ++j) {
      int co = wm * 64 + m * 16 + kq * 4 + j;
      float bv = h ? 0.f : bias[co];
#pragma unroll
      for (int n = 0; n < 2; ++n) {
        int pp = p_base + n * 16 + rl;
        db[(size_t)co * 4096 + pp] = acc[m][n][j] + bv;
      }
    }
  }
}

// ---------------- Kernel 5: out += tmp ----------------
__global__ __launch_bounds__(256) void add_kernel(float* __restrict__ out,
                                                  const float* __restrict__ tmp)
{
  size_t i = ((size_t)blockIdx.x * 256 + threadIdx.x) * 4;
  float4v a = *(const float4v*)(out + i);
  float4v b = *(const float4v*)(tmp + i);
  a += b;
  *(float4v*)(out + i) = a;
}

extern "C" void kernel_launch(void* const* d_in, const int* in_sizes, int n_in,
                              void* d_out, int out_size, void* d_ws, size_t ws_size,
                              hipStream_t stream) {
  const float* x       = (const float*)d_in[0];
  const float* weight  = (const float*)d_in[1];
  const float* bias    = (const float*)d_in[2];
  const float* off_dw  = (const float*)d_in[3];
  const float* off_pw  = (const float*)d_in[4];
  const float* mask_dw = (const float*)d_in[5];
  const float* mask_pw = (const float*)d_in[6];

  // ws layout: rec 2MB @0 | wb 1.18MB @2,097,152 | xt 8.39MB @3,276,800 |
  //            part 33.5MB @11,665,408 (tmp 16.78MB aliases part; part is
  //            consumed by reduce before gemm writes tmp) => 45,219,840 B
  if (ws_size < 45219840ull) return;
  float* rec  = (float*)d_ws;
  u16*   wb   = (u16*)((char*)d_ws + 2097152);
  u16*   xt   = (u16*)((char*)d_ws + 3276800);
  float* part = (float*)((char*)d_ws + 11665408);
  float* tmp  = part;
  float* out  = (float*)d_out;

  wconv_kernel<<<dim3(2304), dim3(256), 0, stream>>>(weight, wb);
  offmask_part_kernel<<<dim3(NPIX / 256, SPLIT), dim3(256), 0, stream>>>(
      x, off_dw, off_pw, mask_dw, mask_pw, part);
  offmask_reduce_kernel<<<dim3(NPIX * 32 / 256), dim3(256), 0, stream>>>(part, rec);
  xpose_kernel<<<dim3(64, 4, 4), dim3(256), 0, stream>>>(x, xt);
  gemm_fused_kernel<<<dim3(512), dim3(512), 0, stream>>>(wb, xt, rec, bias, out, tmp);
  add_kernel<<<dim3(COUT * NPIX / 4 / 256), dim3(256), 0, stream>>>(out, tmp);
}